// Round 2
// baseline (978.885 us; speedup 1.0000x reference)
//
#include <hip/hip_runtime.h>
#include <math.h>
#include <float.h>

// GNN layer, fp32, lean-CSR (atomic-free segment reductions).
// K0 k_tables : s2[rel]=rela@Wr, s3[b]=rela[q_rel[b]]@Wqr_w+b          (tiny)
// K1 k_proj   : P = hidden@Ws (N x 5)
// K2 k_hist   : cnt[obj]++, cnt[N+sub]++
// K3 scan     : exclusive scan of cnt (2N, concatenated) -> off; off[N]==E
// K4 k_scatter: per edge: alpha from P/s2/s3; rec_obj[p]={sub,rel,alpha},
//               rec_sub[q]={obj,sub}  (cursor atomics on copy of off)
// K5 k_agg    : wave/8-nodes (by obj-CSR): max over edges of alpha*(hs-hr) -> agg
// K6 k_mm_uv  : wave/node, lane=col: hn = agg@Wh -> d_out; u/v via shfl reduce
// K7 k_scores : stream rec_sub: s=leaky(u[sub]+v[obj]+b) -> scores[pos]; softmax partials
// K8 k_softmax_final : gmax, gsum
// K8b k_expw  : scores[p] = exp(scores[p]-gmax)  (in place)
// K9 k_aggsum : wave/8-nodes (by sub-CSR): t=sum w*hn[obj], wsum=sum w (unnormalized)
// K10 k_mm_bias: wave/node, lane=col: out = (t@Wnode_w + wsum*Wnode_b) / gsum

#define SCAN_BLK 256
#define SCAN_ITEMS 4
#define SCAN_CHUNK (SCAN_BLK * SCAN_ITEMS)
#define SOFT_G 2048
#define NPW 8        // nodes per wave in batched CSR kernels
#define MM_BLOCKS 2048

// ---------- K0
__global__ void k_tables(const float* __restrict__ rela, const float* __restrict__ Wr,
                         const float* __restrict__ Wqr_w, const float* __restrict__ Wqr_b,
                         const int* __restrict__ q_rel,
                         float* __restrict__ s2, float* __restrict__ s3,
                         int nrel, int batch) {
  int tid = blockIdx.x * blockDim.x + threadIdx.x;
  int stride = gridDim.x * blockDim.x;
  for (int idx = tid; idx < nrel * 5; idx += stride) {
    int r = idx / 5, j = idx % 5;
    float acc = 0.f;
    for (int k = 0; k < 64; k++) acc += rela[r * 64 + k] * Wr[k * 5 + j];
    s2[idx] = acc;
  }
  for (int idx = tid; idx < batch * 5; idx += stride) {
    int b = idx / 5, j = idx % 5;
    int qr = q_rel[b];
    float acc = Wqr_b[j];
    for (int k = 0; k < 64; k++) acc += rela[qr * 64 + k] * Wqr_w[k * 5 + j];
    s3[idx] = acc;
  }
}

// ---------- K1: P = hidden @ Ws
__global__ void __launch_bounds__(256, 2)
k_proj(const float* __restrict__ hidden, const float* __restrict__ Ws_g,
       float* __restrict__ P, int N) {
  int n = blockIdx.x * blockDim.x + threadIdx.x;
  if (n >= N) return;
  float hs[64];
  const float4* h4 = (const float4*)(hidden + (size_t)n * 64);
#pragma unroll
  for (int k4 = 0; k4 < 16; k4++) {
    float4 h = h4[k4];
    hs[k4 * 4 + 0] = h.x; hs[k4 * 4 + 1] = h.y; hs[k4 * 4 + 2] = h.z; hs[k4 * 4 + 3] = h.w;
  }
  float acc[5] = {0.f, 0.f, 0.f, 0.f, 0.f};
#pragma unroll
  for (int k = 0; k < 64; k++) {
    float h = hs[k];
#pragma unroll
    for (int j = 0; j < 5; j++) acc[j] += h * Ws_g[k * 5 + j];  // uniform idx -> s_load
  }
#pragma unroll
  for (int j = 0; j < 5; j++) P[(size_t)n * 5 + j] = acc[j];
}

// ---------- K2
__global__ void k_hist(const int* __restrict__ edges, int* __restrict__ cnt, int E, int N) {
  int e = blockIdx.x * blockDim.x + threadIdx.x;
  if (e < E) {
    int sub = edges[e * 6 + 4];
    int obj = edges[e * 6 + 5];
    atomicAdd(&cnt[obj], 1);
    atomicAdd(&cnt[N + sub], 1);
  }
}

// ---------- K3a
__global__ void k_scan_partial(const int* __restrict__ cnt, int* __restrict__ part, int n) {
  __shared__ int sdata[SCAN_BLK];
  int base = blockIdx.x * SCAN_CHUNK + threadIdx.x * SCAN_ITEMS;
  int s = 0;
#pragma unroll
  for (int j = 0; j < SCAN_ITEMS; j++) { int i = base + j; if (i < n) s += cnt[i]; }
  sdata[threadIdx.x] = s;
  __syncthreads();
  for (int d = SCAN_BLK / 2; d > 0; d >>= 1) {
    if (threadIdx.x < d) sdata[threadIdx.x] += sdata[threadIdx.x + d];
    __syncthreads();
  }
  if (threadIdx.x == 0) part[blockIdx.x] = sdata[0];
}

// ---------- K3b (nblk <= 1024)
__global__ void k_scan_top(int* part, int nblk) {
  __shared__ int lds[1024];
  int tid = threadIdx.x;
  int v = (tid < nblk) ? part[tid] : 0;
  lds[tid] = v;
  __syncthreads();
  for (int d = 1; d < 1024; d <<= 1) {
    int t = (tid >= d) ? lds[tid - d] : 0;
    __syncthreads();
    lds[tid] += t;
    __syncthreads();
  }
  if (tid < nblk) part[tid] = lds[tid] - v;  // exclusive
}

// ---------- K3c
__global__ void k_scan_final(const int* __restrict__ cnt, const int* __restrict__ part,
                             int* __restrict__ off, int n) {
  __shared__ int lds[SCAN_BLK];
  int tid = threadIdx.x;
  int base = blockIdx.x * SCAN_CHUNK + tid * SCAN_ITEMS;
  int c[SCAN_ITEMS];
  int s = 0;
#pragma unroll
  for (int j = 0; j < SCAN_ITEMS; j++) { int i = base + j; c[j] = (i < n) ? cnt[i] : 0; s += c[j]; }
  int v = s;
  lds[tid] = s;
  __syncthreads();
  for (int d = 1; d < SCAN_BLK; d <<= 1) {
    int t = (tid >= d) ? lds[tid - d] : 0;
    __syncthreads();
    lds[tid] += t;
    __syncthreads();
  }
  int run = part[blockIdx.x] + (lds[tid] - v);
#pragma unroll
  for (int j = 0; j < SCAN_ITEMS; j++) { int i = base + j; if (i < n) off[i] = run; run += c[j]; }
}

// ---------- K4: alpha + scatter packed records
__global__ void k_scatter(const int* __restrict__ edges, const float* __restrict__ P,
                          const float* __restrict__ s2, const float* __restrict__ s3,
                          const float* __restrict__ walpha_w, const float* __restrict__ walpha_b,
                          int* __restrict__ cur, int4* __restrict__ rec_obj,
                          int2* __restrict__ rec_sub, int E, int N) {
  int e = blockIdx.x * blockDim.x + threadIdx.x;
  if (e >= E) return;
  int ridx = edges[e * 6 + 0];
  int rel  = edges[e * 6 + 2];
  int sub  = edges[e * 6 + 4];
  int obj  = edges[e * 6 + 5];
  float z = walpha_b[0];
#pragma unroll
  for (int j = 0; j < 5; j++) {
    float vj = P[(size_t)sub * 5 + j] + s2[rel * 5 + j] + s3[ridx * 5 + j];
    z += fmaxf(vj, 0.f) * walpha_w[j];
  }
  float a = 1.f / (1.f + expf(-z));
  int p = atomicAdd(&cur[obj], 1);
  rec_obj[p] = make_int4(sub, rel, __float_as_int(a), 0);
  int q = atomicAdd(&cur[N + sub], 1) - E;
  rec_sub[q] = make_int2(obj, sub);
}

// ---------- K5: segment_max by obj (atomic-free, wave/NPW-nodes)
__global__ void k_agg(const int* __restrict__ off, const int4* __restrict__ rec_obj,
                      const float* __restrict__ hidden, const float* __restrict__ rela,
                      float* __restrict__ agg, int N) {
  int lane = threadIdx.x & 63;
  int wid  = blockIdx.x * (blockDim.x >> 6) + (threadIdx.x >> 6);
  int node0 = wid * NPW;
  if (node0 >= N) return;
  int ov = 0;
  if (lane <= NPW) {
    int idx = node0 + lane;
    if (idx > N) idx = N;
    ov = off[idx];
  }
  int B   = __shfl(ov, 0);
  int End = __shfl(ov, NPW);
  int lbase = B;
  int rx = 0, ry = 0; float rz = 0.f;
  {
    int p = lbase + lane;
    if (p < End) { int4 r = rec_obj[p]; rx = r.x; ry = r.y; rz = __int_as_float(r.z); }
  }
  int cur = B;
  for (int i = 0; i < NPW; i++) {
    int node = node0 + i;
    if (node >= N) break;
    int en = __shfl(ov, i + 1);
    int bst = cur;
    float vmax = -FLT_MAX;
    while (cur < en) {
      int idx = cur - lbase;
      if (idx >= 64) {           // wave-uniform reload of next 64 records
        lbase += 64;
        int p = lbase + lane;
        if (p < End) { int4 r = rec_obj[p]; rx = r.x; ry = r.y; rz = __int_as_float(r.z); }
        idx = 0;
      }
      int sub = __shfl(rx, idx);
      int rel = __shfl(ry, idx);
      float a = __shfl(rz, idx);
      float x = a * (hidden[(size_t)sub * 64 + lane] - rela[rel * 64 + lane]);
      vmax = fmaxf(vmax, x);
      cur++;
    }
    agg[(size_t)node * 64 + lane] = (en > bst) ? vmax : 0.f;
  }
}

// ---------- K6: wave/node, lane=col. hn = agg@Wh; u/v via shfl reduce.
// W column hoisted to 64 VGPRs; per node: 1 coalesced row load, 64x{readlane+fma},
// 1 coalesced row store. No write amplification.
__global__ void __launch_bounds__(256, 4)
k_mm_uv(const float* __restrict__ A, const float* __restrict__ W, const float* __restrict__ fw,
        float* __restrict__ hn, float* __restrict__ u, float* __restrict__ v, int N) {
  int lane = threadIdx.x & 63;
  int wid  = blockIdx.x * (blockDim.x >> 6) + (threadIdx.x >> 6);
  int nwaves = gridDim.x * (blockDim.x >> 6);
  float wl[64];
#pragma unroll
  for (int k = 0; k < 64; k++) wl[k] = W[k * 64 + lane];   // coalesced per k
  float fu = fw[lane], fv = fw[64 + lane];
  for (int n = wid; n < N; n += nwaves) {
    float av = A[(size_t)n * 64 + lane];                   // coalesced
    float acc = 0.f;
#pragma unroll
    for (int k = 0; k < 64; k++) {
      float ak = __int_as_float(__builtin_amdgcn_readlane(__float_as_int(av), k));
      acc = fmaf(ak, wl[k], acc);
    }
    hn[(size_t)n * 64 + lane] = acc;                       // coalesced
    float ur = acc * fu, vr = acc * fv;
#pragma unroll
    for (int m = 32; m > 0; m >>= 1) {
      ur += __shfl_xor(ur, m);
      vr += __shfl_xor(vr, m);
    }
    if (lane == 0) { u[n] = ur; v[n] = vr; }
  }
}

// ---------- K7: scores in sub-CSR position order + softmax partials
__global__ void k_scores(const int2* __restrict__ rec_sub, const float* __restrict__ u,
                         const float* __restrict__ v, const float* __restrict__ fb,
                         float* __restrict__ scores, float* __restrict__ pmax,
                         float* __restrict__ psum, int E) {
  __shared__ float red_m[256], red_s[256];
  float b = fb[0];
  float lm = -FLT_MAX, ls = 0.f;
  for (int pos = blockIdx.x * blockDim.x + threadIdx.x; pos < E; pos += gridDim.x * blockDim.x) {
    int2 r = rec_sub[pos];
    float s = u[r.y] + v[r.x] + b;
    s = (s >= 0.f) ? s : 0.2f * s;
    scores[pos] = s;
    if (s > lm) { ls = ls * expf(lm - s) + 1.f; lm = s; }
    else        { ls += expf(s - lm); }
  }
  red_m[threadIdx.x] = lm; red_s[threadIdx.x] = ls;
  __syncthreads();
  for (int d = blockDim.x / 2; d > 0; d >>= 1) {
    if (threadIdx.x < d) {
      float m1 = red_m[threadIdx.x], s1 = red_s[threadIdx.x];
      float m2 = red_m[threadIdx.x + d], s2 = red_s[threadIdx.x + d];
      float m = fmaxf(m1, m2);
      float s = 0.f;
      if (m > -FLT_MAX) s = s1 * expf(m1 - m) + s2 * expf(m2 - m);
      red_m[threadIdx.x] = m; red_s[threadIdx.x] = s;
    }
    __syncthreads();
  }
  if (threadIdx.x == 0) { pmax[blockIdx.x] = red_m[0]; psum[blockIdx.x] = red_s[0]; }
}

// ---------- K8
__global__ void k_softmax_final(const float* __restrict__ pmax, const float* __restrict__ psum,
                                float* __restrict__ scal, int G) {
  __shared__ float red_m[256], red_s[256];
  float lm = -FLT_MAX, ls = 0.f;
  for (int i = threadIdx.x; i < G; i += 256) {
    float m2 = pmax[i], s2 = psum[i];
    if (m2 > lm) { ls = ls * expf(lm - m2) + s2; lm = m2; }
    else         { ls += s2 * expf(m2 - lm); }
  }
  red_m[threadIdx.x] = lm; red_s[threadIdx.x] = ls;
  __syncthreads();
  for (int d = 128; d > 0; d >>= 1) {
    if (threadIdx.x < d) {
      float m1 = red_m[threadIdx.x], s1 = red_s[threadIdx.x];
      float m2 = red_m[threadIdx.x + d], s2 = red_s[threadIdx.x + d];
      float m = fmaxf(m1, m2);
      float s = 0.f;
      if (m > -FLT_MAX) s = s1 * expf(m1 - m) + s2 * expf(m2 - m);
      red_m[threadIdx.x] = m; red_s[threadIdx.x] = s;
    }
    __syncthreads();
  }
  if (threadIdx.x == 0) { scal[0] = red_m[0]; scal[1] = red_s[0]; }
}

// ---------- K8b: scores -> exp(scores - gmax), in place
__global__ void k_expw(float* __restrict__ scores, const float* __restrict__ scal, int E) {
  int i = blockIdx.x * blockDim.x + threadIdx.x;
  if (i < E) scores[i] = expf(scores[i] - scal[0]);
}

// ---------- K9: weighted segment_sum by sub (atomic-free, wave/NPW-nodes); unnormalized
__global__ void k_aggsum(const int* __restrict__ off, const int2* __restrict__ rec_sub,
                         const float* __restrict__ wexp, const float* __restrict__ hn,
                         float* __restrict__ t, float* __restrict__ wsum, int N, int E) {
  int lane = threadIdx.x & 63;
  int wid  = blockIdx.x * (blockDim.x >> 6) + (threadIdx.x >> 6);
  int node0 = wid * NPW;
  if (node0 >= N) return;
  int ov = 0;
  if (lane <= NPW) {
    int idx = node0 + lane;
    ov = (idx >= N) ? E : (off[N + idx] - E);
  }
  int B   = __shfl(ov, 0);
  int End = __shfl(ov, NPW);
  int lbase = B;
  int objr = 0; float wr = 0.f;
  {
    int p = lbase + lane;
    if (p < End) { objr = rec_sub[p].x; wr = wexp[p]; }
  }
  int cur = B;
  for (int i = 0; i < NPW; i++) {
    int node = node0 + i;
    if (node >= N) break;
    int en = __shfl(ov, i + 1);
    float acc = 0.f, wa = 0.f;
    while (cur < en) {
      int idx = cur - lbase;
      if (idx >= 64) {           // wave-uniform reload
        lbase += 64;
        int p = lbase + lane;
        if (p < End) { objr = rec_sub[p].x; wr = wexp[p]; }
        idx = 0;
      }
      int obj = __shfl(objr, idx);
      float ww = __shfl(wr, idx);
      acc += ww * hn[(size_t)obj * 64 + lane];
      wa  += ww;
      cur++;
    }
    t[(size_t)node * 64 + lane] = acc;
    if (lane == 0) wsum[node] = wa;
  }
}

// ---------- K10: wave/node, lane=col. out = (t @ Wnode_w + wsum * Wnode_b) / gsum
__global__ void __launch_bounds__(256, 4)
k_mm_bias(const float* __restrict__ A, const float* __restrict__ W,
          const float* __restrict__ bias, const float* __restrict__ wsum,
          const float* __restrict__ scal, float* __restrict__ C, int N) {
  int lane = threadIdx.x & 63;
  int wid  = blockIdx.x * (blockDim.x >> 6) + (threadIdx.x >> 6);
  int nwaves = gridDim.x * (blockDim.x >> 6);
  float wl[64];
#pragma unroll
  for (int k = 0; k < 64; k++) wl[k] = W[k * 64 + lane];   // coalesced per k
  float bl = bias[lane];
  float inv = 1.f / scal[1];
  for (int n = wid; n < N; n += nwaves) {
    float av = A[(size_t)n * 64 + lane];                   // coalesced
    float wsn = wsum[n];
    float acc = wsn * bl;
#pragma unroll
    for (int k = 0; k < 64; k++) {
      float ak = __int_as_float(__builtin_amdgcn_readlane(__float_as_int(av), k));
      acc = fmaf(ak, wl[k], acc);
    }
    C[(size_t)n * 64 + lane] = acc * inv;                  // coalesced
  }
}

extern "C" void kernel_launch(void* const* d_in, const int* in_sizes, int n_in,
                              void* d_out, int out_size, void* d_ws, size_t ws_size,
                              hipStream_t stream) {
  const float* hidden    = (const float*)d_in[0];
  const float* rela      = (const float*)d_in[1];
  const float* Ws        = (const float*)d_in[2];
  const float* Wr        = (const float*)d_in[3];
  const float* Wqr_w     = (const float*)d_in[4];
  const float* Wqr_b     = (const float*)d_in[5];
  const float* walpha_w  = (const float*)d_in[6];
  const float* walpha_b  = (const float*)d_in[7];
  const float* Wh        = (const float*)d_in[8];
  const float* attn_fc_w = (const float*)d_in[9];
  const float* attn_fc_b = (const float*)d_in[10];
  const float* Wnode_w   = (const float*)d_in[11];
  const float* Wnode_b   = (const float*)d_in[12];
  const int*   q_rel     = (const int*)d_in[14];
  const int*   edges     = (const int*)d_in[15];

  int N = in_sizes[0] / 64;      // 500000
  int E = in_sizes[15] / 6;      // 1000000
  int nrel = in_sizes[1] / 64;   // 401
  int batch = in_sizes[14];      // 32

  char* w = (char*)d_ws;
  size_t o = 0;
  float* aggT    = (float*)(w + o); o += (size_t)N * 64 * 4;   // agg, then t (aliased)
  float* P       = (float*)(w + o); o += (size_t)N * 5 * 4;    // later: u,v alias here
  int4*  rec_obj = (int4*)(w + o);  o += (size_t)E * 16;
  int2*  rec_sub = (int2*)(w + o);  o += (size_t)E * 8;
  int*   cnt     = (int*)(w + o);   o += (size_t)2 * N * 4;    // counts -> cursors; later scores alias
  int*   off     = (int*)(w + o);   o += (size_t)2 * N * 4;
  float* wsum    = (float*)(w + o); o += (size_t)N * 4;
  int*   part    = (int*)(w + o);   o += 1024 * 4;
  float* pmax    = (float*)(w + o); o += SOFT_G * 4;
  float* psum    = (float*)(w + o); o += SOFT_G * 4;
  float* s2t     = (float*)(w + o); o += (size_t)nrel * 5 * 4;
  float* s3t     = (float*)(w + o); o += (size_t)batch * 5 * 4;
  float* scal    = (float*)(w + o); o += 2 * 4;

  float* u = P;                 // P dead after k_scatter
  float* v = P + N;
  float* scores = (float*)cnt;  // cursors dead after k_scatter (E*4 <= 2N*4)
  float* hn = (float*)d_out;    // lives in d_out until K10 overwrites

  k_tables<<<16, 256, 0, stream>>>(rela, Wr, Wqr_w, Wqr_b, q_rel, s2t, s3t, nrel, batch);
  k_proj<<<(N + 255) / 256, 256, 0, stream>>>(hidden, Ws, P, N);
  hipMemsetAsync(cnt, 0, (size_t)2 * N * 4, stream);
  k_hist<<<(E + 255) / 256, 256, 0, stream>>>(edges, cnt, E, N);
  int SCAN_N = 2 * N;
  int nblk = (SCAN_N + SCAN_CHUNK - 1) / SCAN_CHUNK;  // 977 <= 1024
  k_scan_partial<<<nblk, SCAN_BLK, 0, stream>>>(cnt, part, SCAN_N);
  k_scan_top<<<1, 1024, 0, stream>>>(part, nblk);
  k_scan_final<<<nblk, SCAN_BLK, 0, stream>>>(cnt, part, off, SCAN_N);
  hipMemcpyAsync(cnt, off, (size_t)2 * N * 4, hipMemcpyDeviceToDevice, stream);  // cursors
  k_scatter<<<(E + 255) / 256, 256, 0, stream>>>(edges, P, s2t, s3t, walpha_w, walpha_b,
                                                 cnt, rec_obj, rec_sub, E, N);
  // batched CSR kernels: NPW nodes per wave, 4 waves per block
  int csr_blocks = (N + NPW * 4 - 1) / (NPW * 4);
  k_agg<<<csr_blocks, 256, 0, stream>>>(off, rec_obj, hidden, rela, aggT, N);
  k_mm_uv<<<MM_BLOCKS, 256, 0, stream>>>(aggT, Wh, attn_fc_w, hn, u, v, N);
  k_scores<<<SOFT_G, 256, 0, stream>>>(rec_sub, u, v, attn_fc_b, scores, pmax, psum, E);
  k_softmax_final<<<1, 256, 0, stream>>>(pmax, psum, scal, SOFT_G);
  k_expw<<<(E + 255) / 256, 256, 0, stream>>>(scores, scal, E);
  k_aggsum<<<csr_blocks, 256, 0, stream>>>(off, rec_sub, scores /*wexp*/, hn, aggT /*t*/, wsum, N, E);
  k_mm_bias<<<MM_BLOCKS, 256, 0, stream>>>(aggT /*t*/, Wnode_w, Wnode_b, wsum, scal,
                                           (float*)d_out, N);
}

// Round 4
// 887.122 us; speedup vs baseline: 1.1034x; 1.1034x over previous
//
#include <hip/hip_runtime.h>
#include <math.h>
#include <float.h>

// GNN layer, fp32, lean-CSR (atomic-free segment reductions).
// Algebraic fusion: hn = agg@Wh is never materialized.
//   u[n] = (agg[n]@Wh)·fw[:64], v[n] = (agg[n]@Wh)·fw[64:]   (k_uv, exact assoc, regs only)
//   t    = sum w·hn[obj] = (sum w·agg[obj])@Wh               (k_aggsum gathers agg)
//   out  = (t'@Wh@Wnode_w + wsum·b)/gsum = (t'@W2 + wsum·b)/gsum, W2=Wh@Wnode_w (k_fuse)
// K0 k_tables : s2[rel]=rela@Wr, s3[b]=rela[q_rel[b]]@Wqr_w+b          (tiny)
// K0b k_fuse  : W2 = Wh @ Wnode_w                                      (tiny)
// K1 k_proj   : P = hidden@Ws (N x 5)
// K2 k_hist   : cnt[obj]++, cnt[N+sub]++
// K3 scan     : exclusive scan of cnt (2N, concatenated) -> off; off[N]==E
// K4 k_scatter: per edge: alpha from P/s2/s3; rec_obj[p]={sub,rel,alpha},
//               rec_sub[q]={obj,sub}  (cursor atomics on copy of off)
// K5 k_agg    : wave/8-nodes (by obj-CSR): max over edges of alpha*(hs-hr) -> agg
// K6 k_uv     : thread/node: hn-row in regs -> u,v scalars (no hn store)
// K7 k_scores : stream rec_sub: s=leaky(u[sub]+v[obj]+b) -> scores[pos]; softmax partials
// K8 k_softmax_final : gmax, gsum
// K8b k_expw  : scores[p] = exp(scores[p]-gmax)  (in place)
// K9 k_aggsum : wave/8-nodes (by sub-CSR): t'=sum w*agg[obj] -> d_out, wsum=sum w
// K10 k_mm_out: thread/node: out = (t'@W2 + wsum*Wnode_b)/gsum, LDS-staged coalesced
//               writes, in-place on d_out

#define SCAN_BLK 256
#define SCAN_ITEMS 4
#define SCAN_CHUNK (SCAN_BLK * SCAN_ITEMS)
#define SOFT_G 2048
#define NPW 8        // nodes per wave in batched CSR kernels
#define ONB 128      // nodes per block in k_mm_out (32 KB LDS)

// ---------- K0
__global__ void k_tables(const float* __restrict__ rela, const float* __restrict__ Wr,
                         const float* __restrict__ Wqr_w, const float* __restrict__ Wqr_b,
                         const int* __restrict__ q_rel,
                         float* __restrict__ s2, float* __restrict__ s3,
                         int nrel, int batch) {
  int tid = blockIdx.x * blockDim.x + threadIdx.x;
  int stride = gridDim.x * blockDim.x;
  for (int idx = tid; idx < nrel * 5; idx += stride) {
    int r = idx / 5, j = idx % 5;
    float acc = 0.f;
    for (int k = 0; k < 64; k++) acc += rela[r * 64 + k] * Wr[k * 5 + j];
    s2[idx] = acc;
  }
  for (int idx = tid; idx < batch * 5; idx += stride) {
    int b = idx / 5, j = idx % 5;
    int qr = q_rel[b];
    float acc = Wqr_b[j];
    for (int k = 0; k < 64; k++) acc += rela[qr * 64 + k] * Wqr_w[k * 5 + j];
    s3[idx] = acc;
  }
}

// ---------- K0b: W2 = Wh @ Wnode_w  (64x64 @ 64x64, one block)
__global__ void k_fuse(const float* __restrict__ Wh, const float* __restrict__ Wn,
                       float* __restrict__ W2) {
  int tid = threadIdx.x;
  for (int idx = tid; idx < 64 * 64; idx += 256) {
    int k = idx >> 6, m = idx & 63;
    float acc = 0.f;
    for (int j = 0; j < 64; j++) acc += Wh[k * 64 + j] * Wn[j * 64 + m];
    W2[idx] = acc;
  }
}

// ---------- K1: P = hidden @ Ws
__global__ void __launch_bounds__(256, 2)
k_proj(const float* __restrict__ hidden, const float* __restrict__ Ws_g,
       float* __restrict__ P, int N) {
  int n = blockIdx.x * blockDim.x + threadIdx.x;
  if (n >= N) return;
  float hs[64];
  const float4* h4 = (const float4*)(hidden + (size_t)n * 64);
#pragma unroll
  for (int k4 = 0; k4 < 16; k4++) {
    float4 h = h4[k4];
    hs[k4 * 4 + 0] = h.x; hs[k4 * 4 + 1] = h.y; hs[k4 * 4 + 2] = h.z; hs[k4 * 4 + 3] = h.w;
  }
  float acc[5] = {0.f, 0.f, 0.f, 0.f, 0.f};
#pragma unroll
  for (int k = 0; k < 64; k++) {
    float h = hs[k];
#pragma unroll
    for (int j = 0; j < 5; j++) acc[j] += h * Ws_g[k * 5 + j];  // uniform idx -> s_load
  }
#pragma unroll
  for (int j = 0; j < 5; j++) P[(size_t)n * 5 + j] = acc[j];
}

// ---------- K2
__global__ void k_hist(const int* __restrict__ edges, int* __restrict__ cnt, int E, int N) {
  int e = blockIdx.x * blockDim.x + threadIdx.x;
  if (e < E) {
    int sub = edges[e * 6 + 4];
    int obj = edges[e * 6 + 5];
    atomicAdd(&cnt[obj], 1);
    atomicAdd(&cnt[N + sub], 1);
  }
}

// ---------- K3a
__global__ void k_scan_partial(const int* __restrict__ cnt, int* __restrict__ part, int n) {
  __shared__ int sdata[SCAN_BLK];
  int base = blockIdx.x * SCAN_CHUNK + threadIdx.x * SCAN_ITEMS;
  int s = 0;
#pragma unroll
  for (int j = 0; j < SCAN_ITEMS; j++) { int i = base + j; if (i < n) s += cnt[i]; }
  sdata[threadIdx.x] = s;
  __syncthreads();
  for (int d = SCAN_BLK / 2; d > 0; d >>= 1) {
    if (threadIdx.x < d) sdata[threadIdx.x] += sdata[threadIdx.x + d];
    __syncthreads();
  }
  if (threadIdx.x == 0) part[blockIdx.x] = sdata[0];
}

// ---------- K3b (nblk <= 1024)
__global__ void k_scan_top(int* part, int nblk) {
  __shared__ int lds[1024];
  int tid = threadIdx.x;
  int v = (tid < nblk) ? part[tid] : 0;
  lds[tid] = v;
  __syncthreads();
  for (int d = 1; d < 1024; d <<= 1) {
    int t = (tid >= d) ? lds[tid - d] : 0;
    __syncthreads();
    lds[tid] += t;
    __syncthreads();
  }
  if (tid < nblk) part[tid] = lds[tid] - v;  // exclusive
}

// ---------- K3c
__global__ void k_scan_final(const int* __restrict__ cnt, const int* __restrict__ part,
                             int* __restrict__ off, int n) {
  __shared__ int lds[SCAN_BLK];
  int tid = threadIdx.x;
  int base = blockIdx.x * SCAN_CHUNK + tid * SCAN_ITEMS;
  int c[SCAN_ITEMS];
  int s = 0;
#pragma unroll
  for (int j = 0; j < SCAN_ITEMS; j++) { int i = base + j; c[j] = (i < n) ? cnt[i] : 0; s += c[j]; }
  int v = s;
  lds[tid] = s;
  __syncthreads();
  for (int d = 1; d < SCAN_BLK; d <<= 1) {
    int t = (tid >= d) ? lds[tid - d] : 0;
    __syncthreads();
    lds[tid] += t;
    __syncthreads();
  }
  int run = part[blockIdx.x] + (lds[tid] - v);
#pragma unroll
  for (int j = 0; j < SCAN_ITEMS; j++) { int i = base + j; if (i < n) off[i] = run; run += c[j]; }
}

// ---------- K4: alpha + scatter packed records
__global__ void k_scatter(const int* __restrict__ edges, const float* __restrict__ P,
                          const float* __restrict__ s2, const float* __restrict__ s3,
                          const float* __restrict__ walpha_w, const float* __restrict__ walpha_b,
                          int* __restrict__ cur, int4* __restrict__ rec_obj,
                          int2* __restrict__ rec_sub, int E, int N) {
  int e = blockIdx.x * blockDim.x + threadIdx.x;
  if (e >= E) return;
  int ridx = edges[e * 6 + 0];
  int rel  = edges[e * 6 + 2];
  int sub  = edges[e * 6 + 4];
  int obj  = edges[e * 6 + 5];
  float z = walpha_b[0];
#pragma unroll
  for (int j = 0; j < 5; j++) {
    float vj = P[(size_t)sub * 5 + j] + s2[rel * 5 + j] + s3[ridx * 5 + j];
    z += fmaxf(vj, 0.f) * walpha_w[j];
  }
  float a = 1.f / (1.f + expf(-z));
  int p = atomicAdd(&cur[obj], 1);
  rec_obj[p] = make_int4(sub, rel, __float_as_int(a), 0);
  int q = atomicAdd(&cur[N + sub], 1) - E;
  rec_sub[q] = make_int2(obj, sub);
}

// ---------- K5: segment_max by obj (atomic-free, wave/NPW-nodes)
__global__ void k_agg(const int* __restrict__ off, const int4* __restrict__ rec_obj,
                      const float* __restrict__ hidden, const float* __restrict__ rela,
                      float* __restrict__ agg, int N) {
  int lane = threadIdx.x & 63;
  int wid  = blockIdx.x * (blockDim.x >> 6) + (threadIdx.x >> 6);
  int node0 = wid * NPW;
  if (node0 >= N) return;
  int ov = 0;
  if (lane <= NPW) {
    int idx = node0 + lane;
    if (idx > N) idx = N;
    ov = off[idx];
  }
  int B   = __shfl(ov, 0);
  int End = __shfl(ov, NPW);
  int lbase = B;
  int rx = 0, ry = 0; float rz = 0.f;
  {
    int p = lbase + lane;
    if (p < End) { int4 r = rec_obj[p]; rx = r.x; ry = r.y; rz = __int_as_float(r.z); }
  }
  int cur = B;
  for (int i = 0; i < NPW; i++) {
    int node = node0 + i;
    if (node >= N) break;
    int en = __shfl(ov, i + 1);
    int bst = cur;
    float vmax = -FLT_MAX;
    while (cur < en) {
      int idx = cur - lbase;
      if (idx >= 64) {           // wave-uniform reload of next 64 records
        lbase += 64;
        int p = lbase + lane;
        if (p < End) { int4 r = rec_obj[p]; rx = r.x; ry = r.y; rz = __int_as_float(r.z); }
        idx = 0;
      }
      int sub = __shfl(rx, idx);
      int rel = __shfl(ry, idx);
      float a = __shfl(rz, idx);
      float x = a * (hidden[(size_t)sub * 64 + lane] - rela[rel * 64 + lane]);
      vmax = fmaxf(vmax, x);
      cur++;
    }
    agg[(size_t)node * 64 + lane] = (en > bst) ? vmax : 0.f;
  }
}

// ---------- K6: thread/node. hn-row in regs (exact assoc), reduce to u,v. No hn store.
__global__ void __launch_bounds__(256, 2)
k_uv(const float* __restrict__ A, const float* __restrict__ W, const float* __restrict__ fw,
     float* __restrict__ u, float* __restrict__ v, int N) {
  int n = blockIdx.x * blockDim.x + threadIdx.x;
  if (n >= N) return;
  float a[64];
  const float4* A4 = (const float4*)(A + (size_t)n * 64);
#pragma unroll
  for (int k4 = 0; k4 < 16; k4++) {
    float4 h = A4[k4];
    a[k4 * 4 + 0] = h.x; a[k4 * 4 + 1] = h.y; a[k4 * 4 + 2] = h.z; a[k4 * 4 + 3] = h.w;
  }
  float acc[64];
#pragma unroll
  for (int j = 0; j < 64; j++) acc[j] = 0.f;
#pragma unroll
  for (int k = 0; k < 64; k++) {
    float ak = a[k];
#pragma unroll
    for (int j = 0; j < 64; j++) acc[j] += ak * W[k * 64 + j];  // uniform -> s_load
  }
  float uacc = 0.f, vacc = 0.f;
#pragma unroll
  for (int j = 0; j < 64; j++) {
    uacc += acc[j] * fw[j];
    vacc += acc[j] * fw[64 + j];
  }
  u[n] = uacc;
  v[n] = vacc;
}

// ---------- K7: scores in sub-CSR position order + softmax partials
__global__ void k_scores(const int2* __restrict__ rec_sub, const float* __restrict__ u,
                         const float* __restrict__ v, const float* __restrict__ fb,
                         float* __restrict__ scores, float* __restrict__ pmax,
                         float* __restrict__ psum, int E) {
  __shared__ float red_m[256], red_s[256];
  float b = fb[0];
  float lm = -FLT_MAX, ls = 0.f;
  for (int pos = blockIdx.x * blockDim.x + threadIdx.x; pos < E; pos += gridDim.x * blockDim.x) {
    int2 r = rec_sub[pos];
    float s = u[r.y] + v[r.x] + b;
    s = (s >= 0.f) ? s : 0.2f * s;
    scores[pos] = s;
    if (s > lm) { ls = ls * expf(lm - s) + 1.f; lm = s; }
    else        { ls += expf(s - lm); }
  }
  red_m[threadIdx.x] = lm; red_s[threadIdx.x] = ls;
  __syncthreads();
  for (int d = blockDim.x / 2; d > 0; d >>= 1) {
    if (threadIdx.x < d) {
      float m1 = red_m[threadIdx.x], s1 = red_s[threadIdx.x];
      float m2 = red_m[threadIdx.x + d], s2 = red_s[threadIdx.x + d];
      float m = fmaxf(m1, m2);
      float s = 0.f;
      if (m > -FLT_MAX) s = s1 * expf(m1 - m) + s2 * expf(m2 - m);
      red_m[threadIdx.x] = m; red_s[threadIdx.x] = s;
    }
    __syncthreads();
  }
  if (threadIdx.x == 0) { pmax[blockIdx.x] = red_m[0]; psum[blockIdx.x] = red_s[0]; }
}

// ---------- K8
__global__ void k_softmax_final(const float* __restrict__ pmax, const float* __restrict__ psum,
                                float* __restrict__ scal, int G) {
  __shared__ float red_m[256], red_s[256];
  float lm = -FLT_MAX, ls = 0.f;
  for (int i = threadIdx.x; i < G; i += 256) {
    float m2 = pmax[i], s2 = psum[i];
    if (m2 > lm) { ls = ls * expf(lm - m2) + s2; lm = m2; }
    else         { ls += s2 * expf(m2 - lm); }
  }
  red_m[threadIdx.x] = lm; red_s[threadIdx.x] = ls;
  __syncthreads();
  for (int d = 128; d > 0; d >>= 1) {
    if (threadIdx.x < d) {
      float m1 = red_m[threadIdx.x], s1 = red_s[threadIdx.x];
      float m2 = red_m[threadIdx.x + d], s2 = red_s[threadIdx.x + d];
      float m = fmaxf(m1, m2);
      float s = 0.f;
      if (m > -FLT_MAX) s = s1 * expf(m1 - m) + s2 * expf(m2 - m);
      red_m[threadIdx.x] = m; red_s[threadIdx.x] = s;
    }
    __syncthreads();
  }
  if (threadIdx.x == 0) { scal[0] = red_m[0]; scal[1] = red_s[0]; }
}

// ---------- K8b: scores -> exp(scores - gmax), in place
__global__ void k_expw(float* __restrict__ scores, const float* __restrict__ scal, int E) {
  int i = blockIdx.x * blockDim.x + threadIdx.x;
  if (i < E) scores[i] = expf(scores[i] - scal[0]);
}

// ---------- K9: weighted segment_sum by sub (atomic-free, wave/NPW-nodes); unnormalized
// Gathers agg rows (not hn); writes t' into d_out.
__global__ void k_aggsum(const int* __restrict__ off, const int2* __restrict__ rec_sub,
                         const float* __restrict__ wexp, const float* __restrict__ agg,
                         float* __restrict__ t, float* __restrict__ wsum, int N, int E) {
  int lane = threadIdx.x & 63;
  int wid  = blockIdx.x * (blockDim.x >> 6) + (threadIdx.x >> 6);
  int node0 = wid * NPW;
  if (node0 >= N) return;
  int ov = 0;
  if (lane <= NPW) {
    int idx = node0 + lane;
    ov = (idx >= N) ? E : (off[N + idx] - E);
  }
  int B   = __shfl(ov, 0);
  int End = __shfl(ov, NPW);
  int lbase = B;
  int objr = 0; float wr = 0.f;
  {
    int p = lbase + lane;
    if (p < End) { objr = rec_sub[p].x; wr = wexp[p]; }
  }
  int cur = B;
  for (int i = 0; i < NPW; i++) {
    int node = node0 + i;
    if (node >= N) break;
    int en = __shfl(ov, i + 1);
    float acc = 0.f, wa = 0.f;
    while (cur < en) {
      int idx = cur - lbase;
      if (idx >= 64) {           // wave-uniform reload
        lbase += 64;
        int p = lbase + lane;
        if (p < End) { objr = rec_sub[p].x; wr = wexp[p]; }
        idx = 0;
      }
      int obj = __shfl(objr, idx);
      float ww = __shfl(wr, idx);
      acc += ww * agg[(size_t)obj * 64 + lane];
      wa  += ww;
      cur++;
    }
    t[(size_t)node * 64 + lane] = acc;
    if (lane == 0) wsum[node] = wa;
  }
}

// ---------- K10: thread/node, in-place on d_out. out = (t'@W2 + wsum*Wnode_b)/gsum.
// LDS-staged coalesced writes (float4 XOR swizzle: even bank spread both phases).
__global__ void __launch_bounds__(ONB)
k_mm_out(const float* __restrict__ W2, const float* __restrict__ bias,
         const float* __restrict__ wsum, const float* __restrict__ scal,
         float* C, int N) {
  __shared__ float lds[ONB * 64];  // 32 KB
  int tid = threadIdx.x;
  int n0 = blockIdx.x * ONB;
  int n = n0 + tid;
  float inv = 1.f / scal[1];
  if (n < N) {
    float a[64];
    const float4* A4 = (const float4*)(C + (size_t)n * 64);
#pragma unroll
    for (int q = 0; q < 16; q++) {
      float4 h = A4[q];
      a[q * 4 + 0] = h.x; a[q * 4 + 1] = h.y; a[q * 4 + 2] = h.z; a[q * 4 + 3] = h.w;
    }
    float wsn = wsum[n];
    float acc[64];
#pragma unroll
    for (int j = 0; j < 64; j++) acc[j] = wsn * bias[j];  // uniform -> s_load
#pragma unroll
    for (int k = 0; k < 64; k++) {
      float ak = a[k];
#pragma unroll
      for (int j = 0; j < 64; j++) acc[j] += ak * W2[k * 64 + j];  // uniform -> s_load
    }
    // stage row to LDS, float4-granule XOR swizzle
#pragma unroll
    for (int g = 0; g < 16; g++) {
      int pos = g ^ (tid & 15);
      *(float4*)&lds[tid * 64 + pos * 4] =
          make_float4(acc[g * 4] * inv, acc[g * 4 + 1] * inv,
                      acc[g * 4 + 2] * inv, acc[g * 4 + 3] * inv);
    }
  }
  __syncthreads();
  // block-contiguous coalesced copy-out (ONB*64 floats = ONB*16 float4)
  float4* Cg = (float4*)(C + (size_t)n0 * 64);
#pragma unroll
  for (int i = 0; i < 16; i++) {
    int f = tid + ONB * i;      // linear float4 index within block range
    int row = f >> 4, c4 = f & 15;
    if (n0 + row < N) {
      int pos = c4 ^ (row & 15);
      Cg[f] = *(float4*)&lds[row * 64 + pos * 4];
    }
  }
}

extern "C" void kernel_launch(void* const* d_in, const int* in_sizes, int n_in,
                              void* d_out, int out_size, void* d_ws, size_t ws_size,
                              hipStream_t stream) {
  const float* hidden    = (const float*)d_in[0];
  const float* rela      = (const float*)d_in[1];
  const float* Ws        = (const float*)d_in[2];
  const float* Wr        = (const float*)d_in[3];
  const float* Wqr_w     = (const float*)d_in[4];
  const float* Wqr_b     = (const float*)d_in[5];
  const float* walpha_w  = (const float*)d_in[6];
  const float* walpha_b  = (const float*)d_in[7];
  const float* Wh        = (const float*)d_in[8];
  const float* attn_fc_w = (const float*)d_in[9];
  const float* attn_fc_b = (const float*)d_in[10];
  const float* Wnode_w   = (const float*)d_in[11];
  const float* Wnode_b   = (const float*)d_in[12];
  const int*   q_rel     = (const int*)d_in[14];
  const int*   edges     = (const int*)d_in[15];

  int N = in_sizes[0] / 64;      // 500000
  int E = in_sizes[15] / 6;      // 1000000
  int nrel = in_sizes[1] / 64;   // 401
  int batch = in_sizes[14];      // 32

  // workspace layout: every buffer 256 B aligned
  char* w = (char*)d_ws;
  size_t o = 0;
  #define WS_ALLOC(ptr_t, name, bytes) \
    ptr_t name = (ptr_t)(w + o); o = (o + (size_t)(bytes) + 255) & ~(size_t)255;
  WS_ALLOC(float*, aggT,    (size_t)N * 64 * 4)    // agg (stays live through K9)
  WS_ALLOC(float*, P,       (size_t)N * 5 * 4)     // later: u,v alias here
  WS_ALLOC(int4*,  rec_obj, (size_t)E * 16)
  WS_ALLOC(int2*,  rec_sub, (size_t)E * 8)
  WS_ALLOC(int*,   cnt,     (size_t)2 * N * 4)     // counts -> cursors; later scores alias
  WS_ALLOC(int*,   off,     (size_t)2 * N * 4)
  WS_ALLOC(float*, wsum,    (size_t)N * 4)
  WS_ALLOC(int*,   part,    1024 * 4)
  WS_ALLOC(float*, pmax,    SOFT_G * 4)
  WS_ALLOC(float*, psum,    SOFT_G * 4)
  WS_ALLOC(float*, s2t,     (size_t)nrel * 5 * 4)
  WS_ALLOC(float*, s3t,     (size_t)batch * 5 * 4)
  WS_ALLOC(float*, scal,    2 * 4)
  WS_ALLOC(float*, W2,      64 * 64 * 4)
  #undef WS_ALLOC

  float* u = P;                 // P dead after k_scatter
  float* v = P + N;
  float* scores = (float*)cnt;  // cursors dead after k_scatter (E*4 <= 2N*4)
  float* tbuf = (float*)d_out;  // t' lives in d_out; K10 transforms in place

  k_tables<<<16, 256, 0, stream>>>(rela, Wr, Wqr_w, Wqr_b, q_rel, s2t, s3t, nrel, batch);
  k_fuse<<<1, 256, 0, stream>>>(Wh, Wnode_w, W2);
  k_proj<<<(N + 255) / 256, 256, 0, stream>>>(hidden, Ws, P, N);
  hipMemsetAsync(cnt, 0, (size_t)2 * N * 4, stream);
  k_hist<<<(E + 255) / 256, 256, 0, stream>>>(edges, cnt, E, N);
  int SCAN_N = 2 * N;
  int nblk = (SCAN_N + SCAN_CHUNK - 1) / SCAN_CHUNK;  // 977 <= 1024
  k_scan_partial<<<nblk, SCAN_BLK, 0, stream>>>(cnt, part, SCAN_N);
  k_scan_top<<<1, 1024, 0, stream>>>(part, nblk);
  k_scan_final<<<nblk, SCAN_BLK, 0, stream>>>(cnt, part, off, SCAN_N);
  hipMemcpyAsync(cnt, off, (size_t)2 * N * 4, hipMemcpyDeviceToDevice, stream);  // cursors
  k_scatter<<<(E + 255) / 256, 256, 0, stream>>>(edges, P, s2t, s3t, walpha_w, walpha_b,
                                                 cnt, rec_obj, rec_sub, E, N);
  // batched CSR kernels: NPW nodes per wave, 4 waves per block
  int csr_blocks = (N + NPW * 4 - 1) / (NPW * 4);
  k_agg<<<csr_blocks, 256, 0, stream>>>(off, rec_obj, hidden, rela, aggT, N);
  k_uv<<<(N + 255) / 256, 256, 0, stream>>>(aggT, Wh, attn_fc_w, u, v, N);
  k_scores<<<SOFT_G, 256, 0, stream>>>(rec_sub, u, v, attn_fc_b, scores, pmax, psum, E);
  k_softmax_final<<<1, 256, 0, stream>>>(pmax, psum, scal, SOFT_G);
  k_expw<<<(E + 255) / 256, 256, 0, stream>>>(scores, scal, E);
  k_aggsum<<<csr_blocks, 256, 0, stream>>>(off, rec_sub, scores /*wexp*/, aggT, tbuf, wsum, N, E);
  k_mm_out<<<(N + ONB - 1) / ONB, ONB, 0, stream>>>(W2, Wnode_b, wsum, scal, (float*)d_out, N);
}

// Round 5
// 784.803 us; speedup vs baseline: 1.2473x; 1.1304x over previous
//
#include <hip/hip_runtime.h>
#include <math.h>
#include <float.h>

// GNN layer, fp32, lean-CSR (atomic-free segment reductions).
// Algebraic fusion: hn = agg@Wh is NEVER materialized, and the output GEMM is
// pushed BEFORE the gather:
//   u[n]  = agg[n]·fu,  fu = Wh@fw[:64]   (k_fuse precomputes fu,fv)
//   v[n]  = agg[n]·fv,  fv = Wh@fw[64:]
//   agg2  = agg@W2,     W2 = Wh@Wnode_w   (k_trans, in-place on agg)
//   out   = (sum_e w·agg2[obj_e] + (sum_e w)·Wnode_b)/gsum   (k_aggsum epilogue)
// K0 k_tables : s2[rel]=rela@Wr, s3[b]=rela[q_rel[b]]@Wqr_w+b          (tiny)
// K0b k_fuse  : W2 = Wh@Wnode_w; fu,fv = Wh@attn_fc_w halves           (tiny)
// K1 k_proj   : P = hidden@Ws (N x 5)
// K2 k_hist   : cnt[obj]++, cnt[N+sub]++
// K3 scan     : exclusive scan of cnt (2N, concatenated) -> off; off[N]==E
// K4 k_scatter: per edge: alpha from P/s2/s3; rec_obj[p]={sub,rel,alpha},
//               rec_sub[q]={obj,sub}  (cursor atomics on copy of off)
// K5 k_agg    : wave/8-nodes (by obj-CSR): max over edges of alpha*(hs-hr) -> agg
// K6 k_trans  : thread/node: u,v dots + agg2 = agg@W2 in place (two-phase 16KB
//               LDS-staged coalesced writes)
// K7 k_scores : stream rec_sub: s=leaky(u[sub]+v[obj]+b) -> scores[pos]; softmax partials
// K8 k_softmax_final : gmax, gsum
// K8b k_expw  : scores[p] = exp(scores[p]-gmax)  (in place)
// K9 k_aggsum : wave/8-nodes (by sub-CSR): out = (sum w*agg2[obj] + wa*b)/gsum -> d_out

#define SCAN_BLK 256
#define SCAN_ITEMS 4
#define SCAN_CHUNK (SCAN_BLK * SCAN_ITEMS)
#define SOFT_G 2048
#define NPW 8        // nodes per wave in batched CSR kernels

// ---------- K0
__global__ void k_tables(const float* __restrict__ rela, const float* __restrict__ Wr,
                         const float* __restrict__ Wqr_w, const float* __restrict__ Wqr_b,
                         const int* __restrict__ q_rel,
                         float* __restrict__ s2, float* __restrict__ s3,
                         int nrel, int batch) {
  int tid = blockIdx.x * blockDim.x + threadIdx.x;
  int stride = gridDim.x * blockDim.x;
  for (int idx = tid; idx < nrel * 5; idx += stride) {
    int r = idx / 5, j = idx % 5;
    float acc = 0.f;
    for (int k = 0; k < 64; k++) acc += rela[r * 64 + k] * Wr[k * 5 + j];
    s2[idx] = acc;
  }
  for (int idx = tid; idx < batch * 5; idx += stride) {
    int b = idx / 5, j = idx % 5;
    int qr = q_rel[b];
    float acc = Wqr_b[j];
    for (int k = 0; k < 64; k++) acc += rela[qr * 64 + k] * Wqr_w[k * 5 + j];
    s3[idx] = acc;
  }
}

// ---------- K0b: W2 = Wh @ Wnode_w (64x64); fu,fv = Wh @ attn_fc_w halves
__global__ void k_fuse(const float* __restrict__ Wh, const float* __restrict__ Wn,
                       const float* __restrict__ fw,
                       float* __restrict__ W2, float* __restrict__ fuv) {
  int tid = threadIdx.x;
  for (int idx = tid; idx < 64 * 64; idx += 256) {
    int k = idx >> 6, m = idx & 63;
    float acc = 0.f;
    for (int j = 0; j < 64; j++) acc += Wh[k * 64 + j] * Wn[j * 64 + m];
    W2[idx] = acc;
  }
  if (tid < 128) {
    int k = tid & 63, h = tid >> 6;  // h=0: fu, h=1: fv
    float acc = 0.f;
    for (int j = 0; j < 64; j++) acc += Wh[k * 64 + j] * fw[h * 64 + j];
    fuv[h * 64 + k] = acc;
  }
}

// ---------- K1: P = hidden @ Ws
__global__ void __launch_bounds__(256, 2)
k_proj(const float* __restrict__ hidden, const float* __restrict__ Ws_g,
       float* __restrict__ P, int N) {
  int n = blockIdx.x * blockDim.x + threadIdx.x;
  if (n >= N) return;
  float hs[64];
  const float4* h4 = (const float4*)(hidden + (size_t)n * 64);
#pragma unroll
  for (int k4 = 0; k4 < 16; k4++) {
    float4 h = h4[k4];
    hs[k4 * 4 + 0] = h.x; hs[k4 * 4 + 1] = h.y; hs[k4 * 4 + 2] = h.z; hs[k4 * 4 + 3] = h.w;
  }
  float acc[5] = {0.f, 0.f, 0.f, 0.f, 0.f};
#pragma unroll
  for (int k = 0; k < 64; k++) {
    float h = hs[k];
#pragma unroll
    for (int j = 0; j < 5; j++) acc[j] += h * Ws_g[k * 5 + j];  // uniform idx -> s_load
  }
#pragma unroll
  for (int j = 0; j < 5; j++) P[(size_t)n * 5 + j] = acc[j];
}

// ---------- K2
__global__ void k_hist(const int* __restrict__ edges, int* __restrict__ cnt, int E, int N) {
  int e = blockIdx.x * blockDim.x + threadIdx.x;
  if (e < E) {
    int sub = edges[e * 6 + 4];
    int obj = edges[e * 6 + 5];
    atomicAdd(&cnt[obj], 1);
    atomicAdd(&cnt[N + sub], 1);
  }
}

// ---------- K3a
__global__ void k_scan_partial(const int* __restrict__ cnt, int* __restrict__ part, int n) {
  __shared__ int sdata[SCAN_BLK];
  int base = blockIdx.x * SCAN_CHUNK + threadIdx.x * SCAN_ITEMS;
  int s = 0;
#pragma unroll
  for (int j = 0; j < SCAN_ITEMS; j++) { int i = base + j; if (i < n) s += cnt[i]; }
  sdata[threadIdx.x] = s;
  __syncthreads();
  for (int d = SCAN_BLK / 2; d > 0; d >>= 1) {
    if (threadIdx.x < d) sdata[threadIdx.x] += sdata[threadIdx.x + d];
    __syncthreads();
  }
  if (threadIdx.x == 0) part[blockIdx.x] = sdata[0];
}

// ---------- K3b (nblk <= 1024)
__global__ void k_scan_top(int* part, int nblk) {
  __shared__ int lds[1024];
  int tid = threadIdx.x;
  int v = (tid < nblk) ? part[tid] : 0;
  lds[tid] = v;
  __syncthreads();
  for (int d = 1; d < 1024; d <<= 1) {
    int t = (tid >= d) ? lds[tid - d] : 0;
    __syncthreads();
    lds[tid] += t;
    __syncthreads();
  }
  if (tid < nblk) part[tid] = lds[tid] - v;  // exclusive
}

// ---------- K3c
__global__ void k_scan_final(const int* __restrict__ cnt, const int* __restrict__ part,
                             int* __restrict__ off, int n) {
  __shared__ int lds[SCAN_BLK];
  int tid = threadIdx.x;
  int base = blockIdx.x * SCAN_CHUNK + tid * SCAN_ITEMS;
  int c[SCAN_ITEMS];
  int s = 0;
#pragma unroll
  for (int j = 0; j < SCAN_ITEMS; j++) { int i = base + j; c[j] = (i < n) ? cnt[i] : 0; s += c[j]; }
  int v = s;
  lds[tid] = s;
  __syncthreads();
  for (int d = 1; d < SCAN_BLK; d <<= 1) {
    int t = (tid >= d) ? lds[tid - d] : 0;
    __syncthreads();
    lds[tid] += t;
    __syncthreads();
  }
  int run = part[blockIdx.x] + (lds[tid] - v);
#pragma unroll
  for (int j = 0; j < SCAN_ITEMS; j++) { int i = base + j; if (i < n) off[i] = run; run += c[j]; }
}

// ---------- K4: alpha + scatter packed records
__global__ void k_scatter(const int* __restrict__ edges, const float* __restrict__ P,
                          const float* __restrict__ s2, const float* __restrict__ s3,
                          const float* __restrict__ walpha_w, const float* __restrict__ walpha_b,
                          int* __restrict__ cur, int4* __restrict__ rec_obj,
                          int2* __restrict__ rec_sub, int E, int N) {
  int e = blockIdx.x * blockDim.x + threadIdx.x;
  if (e >= E) return;
  int ridx = edges[e * 6 + 0];
  int rel  = edges[e * 6 + 2];
  int sub  = edges[e * 6 + 4];
  int obj  = edges[e * 6 + 5];
  float z = walpha_b[0];
#pragma unroll
  for (int j = 0; j < 5; j++) {
    float vj = P[(size_t)sub * 5 + j] + s2[rel * 5 + j] + s3[ridx * 5 + j];
    z += fmaxf(vj, 0.f) * walpha_w[j];
  }
  float a = 1.f / (1.f + expf(-z));
  int p = atomicAdd(&cur[obj], 1);
  rec_obj[p] = make_int4(sub, rel, __float_as_int(a), 0);
  int q = atomicAdd(&cur[N + sub], 1) - E;
  rec_sub[q] = make_int2(obj, sub);
}

// ---------- K5: segment_max by obj (atomic-free, wave/NPW-nodes)
__global__ void k_agg(const int* __restrict__ off, const int4* __restrict__ rec_obj,
                      const float* __restrict__ hidden, const float* __restrict__ rela,
                      float* __restrict__ agg, int N) {
  int lane = threadIdx.x & 63;
  int wid  = blockIdx.x * (blockDim.x >> 6) + (threadIdx.x >> 6);
  int node0 = wid * NPW;
  if (node0 >= N) return;
  int ov = 0;
  if (lane <= NPW) {
    int idx = node0 + lane;
    if (idx > N) idx = N;
    ov = off[idx];
  }
  int B   = __shfl(ov, 0);
  int End = __shfl(ov, NPW);
  int lbase = B;
  int rx = 0, ry = 0; float rz = 0.f;
  {
    int p = lbase + lane;
    if (p < End) { int4 r = rec_obj[p]; rx = r.x; ry = r.y; rz = __int_as_float(r.z); }
  }
  int cur = B;
  for (int i = 0; i < NPW; i++) {
    int node = node0 + i;
    if (node >= N) break;
    int en = __shfl(ov, i + 1);
    int bst = cur;
    float vmax = -FLT_MAX;
    while (cur < en) {
      int idx = cur - lbase;
      if (idx >= 64) {           // wave-uniform reload of next 64 records
        lbase += 64;
        int p = lbase + lane;
        if (p < End) { int4 r = rec_obj[p]; rx = r.x; ry = r.y; rz = __int_as_float(r.z); }
        idx = 0;
      }
      int sub = __shfl(rx, idx);
      int rel = __shfl(ry, idx);
      float a = __shfl(rz, idx);
      float x = a * (hidden[(size_t)sub * 64 + lane] - rela[rel * 64 + lane]);
      vmax = fmaxf(vmax, x);
      cur++;
    }
    agg[(size_t)node * 64 + lane] = (en > bst) ? vmax : 0.f;
  }
}

// ---------- K6: thread/node, IN PLACE on agg. u,v dots + agg2 = agg@W2.
// Two-phase 16 KB LDS staging (64 rows per phase) for coalesced writes;
// in-place safe: every row a block writes was fully loaded by its owner thread
// before the barrier preceding the write.
__global__ void __launch_bounds__(128)
k_trans(float* A, const float* __restrict__ W2, const float* __restrict__ fuv,
        float* __restrict__ u, float* __restrict__ v, int N) {
  __shared__ float lds[64 * 64];  // 16 KB
  int tid = threadIdx.x;
  int n0 = blockIdx.x * 128;
  int n = n0 + tid;
  bool act = (n < N);
  float acc[64];
  if (act) {
    float a[64];
    const float4* A4 = (const float4*)(A + (size_t)n * 64);
#pragma unroll
    for (int q = 0; q < 16; q++) {
      float4 h = A4[q];
      a[q * 4 + 0] = h.x; a[q * 4 + 1] = h.y; a[q * 4 + 2] = h.z; a[q * 4 + 3] = h.w;
    }
    float uacc = 0.f, vacc = 0.f;
#pragma unroll
    for (int k = 0; k < 64; k++) {     // fuv uniform -> s_load
      uacc += a[k] * fuv[k];
      vacc += a[k] * fuv[64 + k];
    }
    u[n] = uacc;
    v[n] = vacc;
#pragma unroll
    for (int j = 0; j < 64; j++) acc[j] = 0.f;
#pragma unroll
    for (int k = 0; k < 64; k++) {
      float ak = a[k];
#pragma unroll
      for (int j = 0; j < 64; j++) acc[j] += ak * W2[k * 64 + j];  // uniform -> s_load
    }
  }
  // two phases: rows [n0, n0+64) then [n0+64, n0+128)
  for (int ph = 0; ph < 2; ph++) {
    if (act && (tid >> 6) == ph) {
      int r = tid & 63;
#pragma unroll
      for (int g = 0; g < 16; g++) {
        int pos = g ^ (tid & 15);   // float4-granule XOR swizzle
        *(float4*)&lds[r * 64 + pos * 4] =
            make_float4(acc[g * 4], acc[g * 4 + 1], acc[g * 4 + 2], acc[g * 4 + 3]);
      }
    }
    __syncthreads();
    float4* Cg = (float4*)(A + (size_t)(n0 + ph * 64) * 64);
#pragma unroll
    for (int i = 0; i < 8; i++) {
      int f = tid + 128 * i;        // 0..1023 float4 within 64-row tile
      int row = f >> 4, c4 = f & 15;
      if (n0 + ph * 64 + row < N) {
        int pos = c4 ^ (row & 15);
        Cg[f] = *(float4*)&lds[row * 64 + pos * 4];
      }
    }
    __syncthreads();
  }
}

// ---------- K7: scores in sub-CSR position order + softmax partials
__global__ void k_scores(const int2* __restrict__ rec_sub, const float* __restrict__ u,
                         const float* __restrict__ v, const float* __restrict__ fb,
                         float* __restrict__ scores, float* __restrict__ pmax,
                         float* __restrict__ psum, int E) {
  __shared__ float red_m[256], red_s[256];
  float b = fb[0];
  float lm = -FLT_MAX, ls = 0.f;
  for (int pos = blockIdx.x * blockDim.x + threadIdx.x; pos < E; pos += gridDim.x * blockDim.x) {
    int2 r = rec_sub[pos];
    float s = u[r.y] + v[r.x] + b;
    s = (s >= 0.f) ? s : 0.2f * s;
    scores[pos] = s;
    if (s > lm) { ls = ls * expf(lm - s) + 1.f; lm = s; }
    else        { ls += expf(s - lm); }
  }
  red_m[threadIdx.x] = lm; red_s[threadIdx.x] = ls;
  __syncthreads();
  for (int d = blockDim.x / 2; d > 0; d >>= 1) {
    if (threadIdx.x < d) {
      float m1 = red_m[threadIdx.x], s1 = red_s[threadIdx.x];
      float m2 = red_m[threadIdx.x + d], s2 = red_s[threadIdx.x + d];
      float m = fmaxf(m1, m2);
      float s = 0.f;
      if (m > -FLT_MAX) s = s1 * expf(m1 - m) + s2 * expf(m2 - m);
      red_m[threadIdx.x] = m; red_s[threadIdx.x] = s;
    }
    __syncthreads();
  }
  if (threadIdx.x == 0) { pmax[blockIdx.x] = red_m[0]; psum[blockIdx.x] = red_s[0]; }
}

// ---------- K8
__global__ void k_softmax_final(const float* __restrict__ pmax, const float* __restrict__ psum,
                                float* __restrict__ scal, int G) {
  __shared__ float red_m[256], red_s[256];
  float lm = -FLT_MAX, ls = 0.f;
  for (int i = threadIdx.x; i < G; i += 256) {
    float m2 = pmax[i], s2 = psum[i];
    if (m2 > lm) { ls = ls * expf(lm - m2) + s2; lm = m2; }
    else         { ls += s2 * expf(m2 - lm); }
  }
  red_m[threadIdx.x] = lm; red_s[threadIdx.x] = ls;
  __syncthreads();
  for (int d = 128; d > 0; d >>= 1) {
    if (threadIdx.x < d) {
      float m1 = red_m[threadIdx.x], s1 = red_s[threadIdx.x];
      float m2 = red_m[threadIdx.x + d], s2 = red_s[threadIdx.x + d];
      float m = fmaxf(m1, m2);
      float s = 0.f;
      if (m > -FLT_MAX) s = s1 * expf(m1 - m) + s2 * expf(m2 - m);
      red_m[threadIdx.x] = m; red_s[threadIdx.x] = s;
    }
    __syncthreads();
  }
  if (threadIdx.x == 0) { scal[0] = red_m[0]; scal[1] = red_s[0]; }
}

// ---------- K8b: scores -> exp(scores - gmax), in place
__global__ void k_expw(float* __restrict__ scores, const float* __restrict__ scal, int E) {
  int i = blockIdx.x * blockDim.x + threadIdx.x;
  if (i < E) scores[i] = expf(scores[i] - scal[0]);
}

// ---------- K9: weighted segment_sum by sub (atomic-free, wave/NPW-nodes)
// Gathers agg2; fused epilogue writes FINAL out = (acc + wa*bias)/gsum.
__global__ void k_aggsum(const int* __restrict__ off, const int2* __restrict__ rec_sub,
                         const float* __restrict__ wexp, const float* __restrict__ agg2,
                         const float* __restrict__ bias, const float* __restrict__ scal,
                         float* __restrict__ out, int N, int E) {
  int lane = threadIdx.x & 63;
  int wid  = blockIdx.x * (blockDim.x >> 6) + (threadIdx.x >> 6);
  int node0 = wid * NPW;
  if (node0 >= N) return;
  float bl = bias[lane];
  float inv = 1.f / scal[1];
  int ov = 0;
  if (lane <= NPW) {
    int idx = node0 + lane;
    ov = (idx >= N) ? E : (off[N + idx] - E);
  }
  int B   = __shfl(ov, 0);
  int End = __shfl(ov, NPW);
  int lbase = B;
  int objr = 0; float wr = 0.f;
  {
    int p = lbase + lane;
    if (p < End) { objr = rec_sub[p].x; wr = wexp[p]; }
  }
  int cur = B;
  for (int i = 0; i < NPW; i++) {
    int node = node0 + i;
    if (node >= N) break;
    int en = __shfl(ov, i + 1);
    float acc = 0.f, wa = 0.f;
    while (cur < en) {
      int idx = cur - lbase;
      if (idx >= 64) {           // wave-uniform reload
        lbase += 64;
        int p = lbase + lane;
        if (p < End) { objr = rec_sub[p].x; wr = wexp[p]; }
        idx = 0;
      }
      int obj = __shfl(objr, idx);
      float ww = __shfl(wr, idx);
      acc += ww * agg2[(size_t)obj * 64 + lane];
      wa  += ww;
      cur++;
    }
    out[(size_t)node * 64 + lane] = (acc + wa * bl) * inv;
  }
}

extern "C" void kernel_launch(void* const* d_in, const int* in_sizes, int n_in,
                              void* d_out, int out_size, void* d_ws, size_t ws_size,
                              hipStream_t stream) {
  const float* hidden    = (const float*)d_in[0];
  const float* rela      = (const float*)d_in[1];
  const float* Ws        = (const float*)d_in[2];
  const float* Wr        = (const float*)d_in[3];
  const float* Wqr_w     = (const float*)d_in[4];
  const float* Wqr_b     = (const float*)d_in[5];
  const float* walpha_w  = (const float*)d_in[6];
  const float* walpha_b  = (const float*)d_in[7];
  const float* Wh        = (const float*)d_in[8];
  const float* attn_fc_w = (const float*)d_in[9];
  const float* attn_fc_b = (const float*)d_in[10];
  const float* Wnode_w   = (const float*)d_in[11];
  const float* Wnode_b   = (const float*)d_in[12];
  const int*   q_rel     = (const int*)d_in[14];
  const int*   edges     = (const int*)d_in[15];

  int N = in_sizes[0] / 64;      // 500000
  int E = in_sizes[15] / 6;      // 1000000
  int nrel = in_sizes[1] / 64;   // 401
  int batch = in_sizes[14];      // 32

  // workspace layout: every buffer 256 B aligned
  char* w = (char*)d_ws;
  size_t o = 0;
  #define WS_ALLOC(ptr_t, name, bytes) \
    ptr_t name = (ptr_t)(w + o); o = (o + (size_t)(bytes) + 255) & ~(size_t)255;
  WS_ALLOC(float*, aggT,    (size_t)N * 64 * 4)    // agg -> agg2 (in place)
  WS_ALLOC(float*, P,       (size_t)N * 5 * 4)     // later: u,v alias here
  WS_ALLOC(int4*,  rec_obj, (size_t)E * 16)
  WS_ALLOC(int2*,  rec_sub, (size_t)E * 8)
  WS_ALLOC(int*,   cnt,     (size_t)2 * N * 4)     // counts -> cursors; later scores alias
  WS_ALLOC(int*,   off,     (size_t)2 * N * 4)
  WS_ALLOC(int*,   part,    1024 * 4)
  WS_ALLOC(float*, pmax,    SOFT_G * 4)
  WS_ALLOC(float*, psum,    SOFT_G * 4)
  WS_ALLOC(float*, s2t,     (size_t)nrel * 5 * 4)
  WS_ALLOC(float*, s3t,     (size_t)batch * 5 * 4)
  WS_ALLOC(float*, scal,    2 * 4)
  WS_ALLOC(float*, W2,      64 * 64 * 4)
  WS_ALLOC(float*, fuv,     2 * 64 * 4)
  #undef WS_ALLOC

  float* u = P;                 // P dead after k_scatter
  float* v = P + N;
  float* scores = (float*)cnt;  // cursors dead after k_scatter (E*4 <= 2N*4)

  k_tables<<<16, 256, 0, stream>>>(rela, Wr, Wqr_w, Wqr_b, q_rel, s2t, s3t, nrel, batch);
  k_fuse<<<1, 256, 0, stream>>>(Wh, Wnode_w, attn_fc_w, W2, fuv);
  k_proj<<<(N + 255) / 256, 256, 0, stream>>>(hidden, Ws, P, N);
  hipMemsetAsync(cnt, 0, (size_t)2 * N * 4, stream);
  k_hist<<<(E + 255) / 256, 256, 0, stream>>>(edges, cnt, E, N);
  int SCAN_N = 2 * N;
  int nblk = (SCAN_N + SCAN_CHUNK - 1) / SCAN_CHUNK;  // 977 <= 1024
  k_scan_partial<<<nblk, SCAN_BLK, 0, stream>>>(cnt, part, SCAN_N);
  k_scan_top<<<1, 1024, 0, stream>>>(part, nblk);
  k_scan_final<<<nblk, SCAN_BLK, 0, stream>>>(cnt, part, off, SCAN_N);
  hipMemcpyAsync(cnt, off, (size_t)2 * N * 4, hipMemcpyDeviceToDevice, stream);  // cursors
  k_scatter<<<(E + 255) / 256, 256, 0, stream>>>(edges, P, s2t, s3t, walpha_w, walpha_b,
                                                 cnt, rec_obj, rec_sub, E, N);
  // batched CSR kernels: NPW nodes per wave, 4 waves per block
  int csr_blocks = (N + NPW * 4 - 1) / (NPW * 4);
  k_agg<<<csr_blocks, 256, 0, stream>>>(off, rec_obj, hidden, rela, aggT, N);
  k_trans<<<(N + 127) / 128, 128, 0, stream>>>(aggT, W2, fuv, u, v, N);
  k_scores<<<SOFT_G, 256, 0, stream>>>(rec_sub, u, v, attn_fc_b, scores, pmax, psum, E);
  k_softmax_final<<<1, 256, 0, stream>>>(pmax, psum, scal, SOFT_G);
  k_expw<<<(E + 255) / 256, 256, 0, stream>>>(scores, scal, E);
  k_aggsum<<<csr_blocks, 256, 0, stream>>>(off, rec_sub, scores /*wexp*/, aggT /*agg2*/,
                                           Wnode_b, scal, (float*)d_out, N, E);
}